// Round 16
// baseline (51.235 us; speedup 1.0000x reference)
//
#include <hip/hip_runtime.h>
#include <math.h>

#define B_TOTAL 16384
#define RR 64
#define KK 256          // 4*R
#define MM 512
#define ROWS 32         // batch rows per block
#define NBLK (B_TOTAL / ROWS)   // 512 blocks = 2/CU, all co-resident
#define NCH 8           // K chunks of 32
#define NNI 4           // 16-col tiles per wave (64 cols/wave, 8 waves)
#define MI 2            // 16-row M-tiles per wave
#define ASTR 264        // A LDS row stride (fp16 elems)
#define INV2PI 0.15915494309189535f

typedef __attribute__((ext_vector_type(8))) _Float16 half8;
typedef __attribute__((ext_vector_type(4))) float floatx4;

// DPP mov with multiplicative identity for invalid/unwritten lanes
template<int CTRL, int RMASK>
static __device__ inline float dpp_mov1(float src) {
    int s = __builtin_bit_cast(int, src);
    int o = __builtin_bit_cast(int, 1.0f);
    int r = __builtin_amdgcn_update_dpp(o, s, CTRL, RMASK, 0xF, false);
    return __builtin_bit_cast(float, r);
}
template<int CTRL>
static __device__ inline float dpp_swap(float src) {
    int s = __builtin_bit_cast(int, src);
    int r = __builtin_amdgcn_update_dpp(s, s, CTRL, 0xF, 0xF, false);
    return __builtin_bit_cast(float, r);
}
static __device__ inline float red16(float x) {
    x += dpp_swap<0xB1>(x);    // quad_perm xor1
    x += dpp_swap<0x4E>(x);    // quad_perm xor2
    x += dpp_swap<0x141>(x);   // row_half_mirror
    x += dpp_swap<0x140>(x);   // row_mirror
    return x;
}

// ---- single fused kernel: S-conv share + gather + stick-break +
//      device barrier + fp16 MFMA + folded-sin + reduce ----
__global__ __launch_bounds__(512, 4)
void nest2_fused(const int* __restrict__ indices,
                 const float* __restrict__ v0, const float* __restrict__ v1,
                 const float* __restrict__ v2, const float* __restrict__ v3,
                 const float* __restrict__ S,
                 const float* __restrict__ bvec, const float* __restrict__ w_mu,
                 _Float16* __restrict__ Bh, float* __restrict__ wa,
                 float* __restrict__ bb2, int* __restrict__ done,
                 float* __restrict__ out)
{
    __shared__ alignas(16) _Float16 Ah[ROWS * ASTR];
    __shared__ float red[8][ROWS];

    const int tid = threadIdx.x;
    const int bid = blockIdx.x;
    const int rowBase = bid * ROWS;
    const int wid  = __builtin_amdgcn_readfirstlane(tid >> 6);   // 0..7
    const int lane = tid & 63;
    const int l15  = lane & 15;
    const int lg   = lane >> 4;
    const int wcol0 = wid * 64;    // this wave's 64-col slice

    #define BOFF(ch, ni) ((((ch) * 4 + lg) * 512 + wcol0 + (ni) * 16 + l15) * 8)

    // ---- phase A: this block's share of producer work ----
    // 32 S-granules -> Bh (fp16 of S/2pi, MFMA B-fragment order)
    if (tid < 32) {
        const int F = bid * 32 + tid;   // F = o*512 + c, 16384 total
        const int o = F >> 9;
        const int c = F & 511;
        const float* src = &S[c * KK + o * 8];
        float v[8];
        *reinterpret_cast<float4*>(&v[0]) = *reinterpret_cast<const float4*>(src);
        *reinterpret_cast<float4*>(&v[4]) = *reinterpret_cast<const float4*>(src + 4);
        half8 hv;
        #pragma unroll
        for (int j = 0; j < 8; ++j)
            hv[j] = (_Float16)(v[j] * INV2PI);
        *reinterpret_cast<half8*>(&Bh[F * 8]) = hv;
    } else if (tid == 32) {
        // one folded epilogue column per block:
        // w1*cos(2pi x)+w2*sin(2pi x) = A*sin(2pi(x+phi'))
        const float w1 = w_mu[bid];
        const float w2 = w_mu[MM + bid];
        wa[bid]  = sqrtf(w1 * w1 + w2 * w2);
        bb2[bid] = bvec[bid] * INV2PI + atan2f(w1, w2) * INV2PI;
    }

    // ---- phase B: gather loads (wave-uniform row addresses -> coalesced) ----
    const int* ip = indices + rowBase * 4 + wid * 16;
    const float* vts[4] = {v0, v1, v2, v3};
    float vh[16];
    #pragma unroll
    for (int it = 0; it < 16; ++it) {
        const int mod = it & 3;            // wid*16 ≡ 0 (mod 4)
        vh[it] = vts[mod][ip[it] * RR + lane];
    }

    // ---- stick-breaking via DPP product-scan -> Ah (fp16) ----
    #pragma unroll
    for (int it = 0; it < 16; ++it) {
        const int p   = wid * 16 + it;     // 128 (row,mod) pairs per block
        const int row = p >> 2;
        const int mod = p & 3;
        const float t  = __expf(vh[it]);                    // e^{vh}
        const float um = __builtin_amdgcn_rcpf(1.f + t);    // sigmoid(-vh)
        float pr = um;                                      // inclusive scan
        pr *= dpp_mov1<0x111, 0xF>(pr);   // row_shr:1
        pr *= dpp_mov1<0x112, 0xF>(pr);   // row_shr:2
        pr *= dpp_mov1<0x114, 0xF>(pr);   // row_shr:4
        pr *= dpp_mov1<0x118, 0xF>(pr);   // row_shr:8
        pr *= dpp_mov1<0x142, 0xA>(pr);   // row_bcast:15
        pr *= dpp_mov1<0x143, 0xC>(pr);   // row_bcast:31
        const float x = t * pr;           // sigmoid(vh) * exclusive-prod
        Ah[row * ASTR + mod * RR + lane] = (_Float16)x;
    }
    __syncthreads();   // Ah ready; phase-A stores drained (barrier waits vmcnt)

    // ---- device-wide producer barrier (all NBLK blocks co-resident) ----
    if (tid == 0) {
        __threadfence();   // write-back this XCD's L2 (release side)
        __hip_atomic_fetch_add(done, 1, __ATOMIC_RELEASE,
                               __HIP_MEMORY_SCOPE_AGENT);
        while (__hip_atomic_load(done, __ATOMIC_RELAXED,
                                 __HIP_MEMORY_SCOPE_AGENT) < NBLK)
            __builtin_amdgcn_s_sleep(32);
        __threadfence();   // acquire side: invalidate stale cached lines
    }
    __syncthreads();

    // ---- epilogue constants (now ready) ----
    float bbv[NNI], wav[NNI];
    #pragma unroll
    for (int ni = 0; ni < NNI; ++ni) {
        const int c = wcol0 + ni * 16 + l15;
        wav[ni] = wa[c];
        bbv[ni] = bb2[c];
    }

    // ---- fp16 MFMA K-loop, register-double-buffered B ----
    floatx4 acc[MI][NNI];
    #pragma unroll
    for (int mi = 0; mi < MI; ++mi)
        #pragma unroll
        for (int ni = 0; ni < NNI; ++ni)
            acc[mi][ni] = (floatx4){0.f, 0.f, 0.f, 0.f};

    half8 b[NNI];
    #pragma unroll
    for (int ni = 0; ni < NNI; ++ni)
        b[ni] = *reinterpret_cast<const half8*>(&Bh[BOFF(0, ni)]);

    #pragma unroll
    for (int ch = 0; ch < NCH; ++ch) {
        half8 ah[MI];
        #pragma unroll
        for (int mi = 0; mi < MI; ++mi)
            ah[mi] = *reinterpret_cast<const half8*>(
                &Ah[(mi * 16 + l15) * ASTR + ch * 32 + lg * 8]);
        half8 bn[NNI];
        if (ch + 1 < NCH) {
            #pragma unroll
            for (int ni = 0; ni < NNI; ++ni)
                bn[ni] = *reinterpret_cast<const half8*>(&Bh[BOFF(ch + 1, ni)]);
        }
        __builtin_amdgcn_s_setprio(1);
        #pragma unroll
        for (int ni = 0; ni < NNI; ++ni)
            #pragma unroll
            for (int mi = 0; mi < MI; ++mi)
                acc[mi][ni] = __builtin_amdgcn_mfma_f32_16x16x32_f16(ah[mi], b[ni], acc[mi][ni], 0, 0, 0);
        __builtin_amdgcn_s_setprio(0);
        if (ch + 1 < NCH) {
            #pragma unroll
            for (int ni = 0; ni < NNI; ++ni)
                b[ni] = bn[ni];
        }
    }

    // ---- epilogue: A*sin(2pi(x+phi')), reduce ----
    float rp[MI][4];
    #pragma unroll
    for (int mi = 0; mi < MI; ++mi)
        #pragma unroll
        for (int r = 0; r < 4; ++r) rp[mi][r] = 0.f;

    #pragma unroll
    for (int ni = 0; ni < NNI; ++ni) {
        #pragma unroll
        for (int mi = 0; mi < MI; ++mi)
            #pragma unroll
            for (int r = 0; r < 4; ++r) {
                const float psi = acc[mi][ni][r] + bbv[ni];   // revolutions
                rp[mi][r] = fmaf(wav[ni], __builtin_amdgcn_sinf(psi), rp[mi][r]);
            }
    }

    #pragma unroll
    for (int mi = 0; mi < MI; ++mi)
        #pragma unroll
        for (int r = 0; r < 4; ++r) {
            const float v = red16(rp[mi][r]);                 // sum over 16 cols
            if (l15 == 0) red[wid][mi * 16 + lg * 4 + r] = v;
        }
    __syncthreads();

    if (tid < ROWS) {
        float s = 0.f;
        #pragma unroll
        for (int w = 0; w < 8; ++w) s += red[w][tid];
        out[rowBase + tid] = 1.f / (1.f + __expf(-s));
    }
    #undef BOFF
}

extern "C" void kernel_launch(void* const* d_in, const int* in_sizes, int n_in,
                              void* d_out, int out_size, void* d_ws, size_t ws_size,
                              hipStream_t stream) {
    const int*   indices = (const int*)d_in[0];
    const float* v0 = (const float*)d_in[1];
    const float* v1 = (const float*)d_in[2];
    const float* v2 = (const float*)d_in[3];
    const float* v3 = (const float*)d_in[4];
    const float* S  = (const float*)d_in[5];
    const float* bb = (const float*)d_in[6];
    const float* w  = (const float*)d_in[7];
    float* out = (float*)d_out;

    char* wsb = (char*)d_ws;
    _Float16* Bh  = (_Float16*)wsb;                  // 256 KB
    float*    wa  = (float*)(wsb + 262144);          // 2 KB
    float*    bb2 = (float*)(wsb + 264192);          // 2 KB
    int*      done= (int*)(wsb + 266240);            // 4 B

    hipMemsetAsync(done, 0, sizeof(int), stream);    // capture-safe reset
    hipLaunchKernelGGL(nest2_fused, dim3(NBLK), dim3(512), 0, stream,
                       indices, v0, v1, v2, v3, S, bb, w,
                       Bh, wa, bb2, done, out);
}

// Round 17
// 49.383 us; speedup vs baseline: 1.0375x; 1.0375x over previous
//
#include <hip/hip_runtime.h>
#include <math.h>

#define B_TOTAL 16384
#define RR 64
#define KK 256          // 4*R
#define MM 512
#define ROWS 32         // batch rows per block
#define NBLK (B_TOTAL / ROWS)   // 512 blocks = 2/CU, all co-resident
#define NCH 8           // K chunks of 32
#define NNI 4           // 16-col tiles per wave (64 cols/wave, 8 waves)
#define MI 2            // 16-row M-tiles per wave
#define ASTR 264        // A LDS row stride (fp16 elems)
#define INV2PI 0.15915494309189535f

typedef __attribute__((ext_vector_type(8))) _Float16 half8;
typedef __attribute__((ext_vector_type(4))) float floatx4;

// DPP mov with multiplicative identity for invalid/unwritten lanes
template<int CTRL, int RMASK>
static __device__ inline float dpp_mov1(float src) {
    int s = __builtin_bit_cast(int, src);
    int o = __builtin_bit_cast(int, 1.0f);
    int r = __builtin_amdgcn_update_dpp(o, s, CTRL, RMASK, 0xF, false);
    return __builtin_bit_cast(float, r);
}
template<int CTRL>
static __device__ inline float dpp_swap(float src) {
    int s = __builtin_bit_cast(int, src);
    int r = __builtin_amdgcn_update_dpp(s, s, CTRL, 0xF, 0xF, false);
    return __builtin_bit_cast(float, r);
}
static __device__ inline float red16(float x) {
    x += dpp_swap<0xB1>(x);    // quad_perm xor1
    x += dpp_swap<0x4E>(x);    // quad_perm xor2
    x += dpp_swap<0x141>(x);   // row_half_mirror
    x += dpp_swap<0x140>(x);   // row_mirror
    return x;
}

// ---- single fused kernel: S-conv share + gather + stick-break +
//      device barrier + fp16 MFMA + folded-sin + reduce ----
__global__ __launch_bounds__(512, 4)
void nest2_fused(const int* __restrict__ indices,
                 const float* __restrict__ v0, const float* __restrict__ v1,
                 const float* __restrict__ v2, const float* __restrict__ v3,
                 const float* __restrict__ S,
                 const float* __restrict__ bvec, const float* __restrict__ w_mu,
                 _Float16* __restrict__ Bh, float* __restrict__ wa,
                 float* __restrict__ bb2, int* __restrict__ done,
                 float* __restrict__ out)
{
    __shared__ alignas(16) _Float16 Ah[ROWS * ASTR];
    __shared__ float red[8][ROWS];

    const int tid = threadIdx.x;
    const int bid = blockIdx.x;
    const int rowBase = bid * ROWS;
    const int wid  = __builtin_amdgcn_readfirstlane(tid >> 6);   // 0..7
    const int lane = tid & 63;
    const int l15  = lane & 15;
    const int lg   = lane >> 4;
    const int wcol0 = wid * 64;    // this wave's 64-col slice

    #define BOFF(ch, ni) ((((ch) * 4 + lg) * 512 + wcol0 + (ni) * 16 + l15) * 8)

    // ---- phase A: this block's share of producer work ----
    // 32 S-granules -> Bh (fp16 of S/2pi, MFMA B-fragment order)
    if (tid < 32) {
        const int F = bid * 32 + tid;   // F = o*512 + c, 16384 total
        const int o = F >> 9;
        const int c = F & 511;
        const float* src = &S[c * KK + o * 8];
        float v[8];
        *reinterpret_cast<float4*>(&v[0]) = *reinterpret_cast<const float4*>(src);
        *reinterpret_cast<float4*>(&v[4]) = *reinterpret_cast<const float4*>(src + 4);
        half8 hv;
        #pragma unroll
        for (int j = 0; j < 8; ++j)
            hv[j] = (_Float16)(v[j] * INV2PI);
        *reinterpret_cast<half8*>(&Bh[F * 8]) = hv;
    } else if (tid == 32) {
        // one folded epilogue column per block:
        // w1*cos(2pi x)+w2*sin(2pi x) = A*sin(2pi(x+phi'))
        const float w1 = w_mu[bid];
        const float w2 = w_mu[MM + bid];
        wa[bid]  = sqrtf(w1 * w1 + w2 * w2);
        bb2[bid] = bvec[bid] * INV2PI + atan2f(w1, w2) * INV2PI;
    }

    // ---- phase B: gather loads (wave-uniform row addresses -> coalesced) ----
    const int* ip = indices + rowBase * 4 + wid * 16;
    const float* vts[4] = {v0, v1, v2, v3};
    float vh[16];
    #pragma unroll
    for (int it = 0; it < 16; ++it) {
        const int mod = it & 3;            // wid*16 ≡ 0 (mod 4)
        vh[it] = vts[mod][ip[it] * RR + lane];
    }

    // ---- stick-breaking via DPP product-scan -> Ah (fp16) ----
    #pragma unroll
    for (int it = 0; it < 16; ++it) {
        const int p   = wid * 16 + it;     // 128 (row,mod) pairs per block
        const int row = p >> 2;
        const int mod = p & 3;
        const float t  = __expf(vh[it]);                    // e^{vh}
        const float um = __builtin_amdgcn_rcpf(1.f + t);    // sigmoid(-vh)
        float pr = um;                                      // inclusive scan
        pr *= dpp_mov1<0x111, 0xF>(pr);   // row_shr:1
        pr *= dpp_mov1<0x112, 0xF>(pr);   // row_shr:2
        pr *= dpp_mov1<0x114, 0xF>(pr);   // row_shr:4
        pr *= dpp_mov1<0x118, 0xF>(pr);   // row_shr:8
        pr *= dpp_mov1<0x142, 0xA>(pr);   // row_bcast:15
        pr *= dpp_mov1<0x143, 0xC>(pr);   // row_bcast:31
        const float x = t * pr;           // sigmoid(vh) * exclusive-prod
        Ah[row * ASTR + mod * RR + lane] = (_Float16)x;
    }
    __syncthreads();   // Ah ready; phase-A stores drained (barrier waits vmcnt)

    // ---- device-wide producer barrier (all NBLK blocks co-resident) ----
    if (tid == 0) {
        __threadfence();   // write-back this XCD's L2 (release side)
        __hip_atomic_fetch_add(done, 1, __ATOMIC_RELEASE,
                               __HIP_MEMORY_SCOPE_AGENT);
        while (__hip_atomic_load(done, __ATOMIC_RELAXED,
                                 __HIP_MEMORY_SCOPE_AGENT) < NBLK)
            __builtin_amdgcn_s_sleep(32);
        __threadfence();   // acquire side: invalidate stale cached lines
    }
    __syncthreads();

    // ---- epilogue constants (now ready) ----
    float bbv[NNI], wav[NNI];
    #pragma unroll
    for (int ni = 0; ni < NNI; ++ni) {
        const int c = wcol0 + ni * 16 + l15;
        wav[ni] = wa[c];
        bbv[ni] = bb2[c];
    }

    // ---- fp16 MFMA K-loop, register-double-buffered B ----
    floatx4 acc[MI][NNI];
    #pragma unroll
    for (int mi = 0; mi < MI; ++mi)
        #pragma unroll
        for (int ni = 0; ni < NNI; ++ni)
            acc[mi][ni] = (floatx4){0.f, 0.f, 0.f, 0.f};

    half8 b[NNI];
    #pragma unroll
    for (int ni = 0; ni < NNI; ++ni)
        b[ni] = *reinterpret_cast<const half8*>(&Bh[BOFF(0, ni)]);

    #pragma unroll
    for (int ch = 0; ch < NCH; ++ch) {
        half8 ah[MI];
        #pragma unroll
        for (int mi = 0; mi < MI; ++mi)
            ah[mi] = *reinterpret_cast<const half8*>(
                &Ah[(mi * 16 + l15) * ASTR + ch * 32 + lg * 8]);
        half8 bn[NNI];
        if (ch + 1 < NCH) {
            #pragma unroll
            for (int ni = 0; ni < NNI; ++ni)
                bn[ni] = *reinterpret_cast<const half8*>(&Bh[BOFF(ch + 1, ni)]);
        }
        __builtin_amdgcn_s_setprio(1);
        #pragma unroll
        for (int ni = 0; ni < NNI; ++ni)
            #pragma unroll
            for (int mi = 0; mi < MI; ++mi)
                acc[mi][ni] = __builtin_amdgcn_mfma_f32_16x16x32_f16(ah[mi], b[ni], acc[mi][ni], 0, 0, 0);
        __builtin_amdgcn_s_setprio(0);
        if (ch + 1 < NCH) {
            #pragma unroll
            for (int ni = 0; ni < NNI; ++ni)
                b[ni] = bn[ni];
        }
    }

    // ---- epilogue: A*sin(2pi(x+phi')), reduce ----
    float rp[MI][4];
    #pragma unroll
    for (int mi = 0; mi < MI; ++mi)
        #pragma unroll
        for (int r = 0; r < 4; ++r) rp[mi][r] = 0.f;

    #pragma unroll
    for (int ni = 0; ni < NNI; ++ni) {
        #pragma unroll
        for (int mi = 0; mi < MI; ++mi)
            #pragma unroll
            for (int r = 0; r < 4; ++r) {
                const float psi = acc[mi][ni][r] + bbv[ni];   // revolutions
                rp[mi][r] = fmaf(wav[ni], __builtin_amdgcn_sinf(psi), rp[mi][r]);
            }
    }

    #pragma unroll
    for (int mi = 0; mi < MI; ++mi)
        #pragma unroll
        for (int r = 0; r < 4; ++r) {
            const float v = red16(rp[mi][r]);                 // sum over 16 cols
            if (l15 == 0) red[wid][mi * 16 + lg * 4 + r] = v;
        }
    __syncthreads();

    if (tid < ROWS) {
        float s = 0.f;
        #pragma unroll
        for (int w = 0; w < 8; ++w) s += red[w][tid];
        out[rowBase + tid] = 1.f / (1.f + __expf(-s));
    }
    #undef BOFF
}

extern "C" void kernel_launch(void* const* d_in, const int* in_sizes, int n_in,
                              void* d_out, int out_size, void* d_ws, size_t ws_size,
                              hipStream_t stream) {
    const int*   indices = (const int*)d_in[0];
    const float* v0 = (const float*)d_in[1];
    const float* v1 = (const float*)d_in[2];
    const float* v2 = (const float*)d_in[3];
    const float* v3 = (const float*)d_in[4];
    const float* S  = (const float*)d_in[5];
    const float* bb = (const float*)d_in[6];
    const float* w  = (const float*)d_in[7];
    float* out = (float*)d_out;

    char* wsb = (char*)d_ws;
    _Float16* Bh  = (_Float16*)wsb;                  // 256 KB
    float*    wa  = (float*)(wsb + 262144);          // 2 KB
    float*    bb2 = (float*)(wsb + 264192);          // 2 KB
    int*      done= (int*)(wsb + 266240);            // 4 B

    hipMemsetAsync(done, 0, sizeof(int), stream);    // capture-safe reset
    hipLaunchKernelGGL(nest2_fused, dim3(NBLK), dim3(512), 0, stream,
                       indices, v0, v1, v2, v3, S, bb, w,
                       Bh, wa, bb2, done, out);
}

// Round 18
// 18.634 us; speedup vs baseline: 2.7496x; 2.6502x over previous
//
#include <hip/hip_runtime.h>
#include <math.h>

#define B_TOTAL 16384
#define RR 64
#define KK 256          // 4*R
#define MM 512
#define ROWS 32         // batch rows per block
#define NCH 8           // K chunks of 32
#define NNI 4           // 16-col tiles per wave (64 cols/wave, 8 waves)
#define MI 2            // 16-row M-tiles per wave
#define ASTR 264        // A LDS row stride (fp16 elems)
#define INV2PI 0.15915494309189535f

typedef __attribute__((ext_vector_type(8))) _Float16 half8;
typedef __attribute__((ext_vector_type(4))) float floatx4;

// DPP mov with multiplicative identity for invalid/unwritten lanes
template<int CTRL, int RMASK>
static __device__ inline float dpp_mov1(float src) {
    int s = __builtin_bit_cast(int, src);
    int o = __builtin_bit_cast(int, 1.0f);
    int r = __builtin_amdgcn_update_dpp(o, s, CTRL, RMASK, 0xF, false);
    return __builtin_bit_cast(float, r);
}
template<int CTRL>
static __device__ inline float dpp_swap(float src) {
    int s = __builtin_bit_cast(int, src);
    int r = __builtin_amdgcn_update_dpp(s, s, CTRL, 0xF, 0xF, false);
    return __builtin_bit_cast(float, r);
}
static __device__ inline float red16(float x) {
    x += dpp_swap<0xB1>(x);    // quad_perm xor1
    x += dpp_swap<0x4E>(x);    // quad_perm xor2
    x += dpp_swap<0x141>(x);   // row_half_mirror
    x += dpp_swap<0x140>(x);   // row_mirror
    return x;
}

// ---- kernel 1: prep.
//  blocks 0..63 : S -> fp16 of S/(2*pi), MFMA B-fragment order
//  block  64    : folded epilogue constants:
//                 w1*cos(2pi x)+w2*sin(2pi x) = A*sin(2pi(x+phi'))
__global__ __launch_bounds__(256)
void prep(const float* __restrict__ S, const float* __restrict__ bvec,
          const float* __restrict__ w_mu,
          _Float16* __restrict__ Bh, float* __restrict__ wa,
          float* __restrict__ bb2)
{
    const int bid = blockIdx.x;
    const int tid = threadIdx.x;
    if (bid < 64) {
        const int F = bid * 256 + tid;   // F = o*512 + c, 16384 total
        const int o = F >> 9;
        const int c = F & 511;
        const float* src = &S[c * KK + o * 8];
        float v[8];
        *reinterpret_cast<float4*>(&v[0]) = *reinterpret_cast<const float4*>(src);
        *reinterpret_cast<float4*>(&v[4]) = *reinterpret_cast<const float4*>(src + 4);
        half8 hv;
        #pragma unroll
        for (int j = 0; j < 8; ++j)
            hv[j] = (_Float16)(v[j] * INV2PI);
        *reinterpret_cast<half8*>(&Bh[F * 8]) = hv;
    } else {
        #pragma unroll
        for (int q = 0; q < 2; ++q) {
            const int c = tid * 2 + q;
            const float w1 = w_mu[c];
            const float w2 = w_mu[MM + c];
            wa[c]  = sqrtf(w1 * w1 + w2 * w2);
            bb2[c] = bvec[c] * INV2PI + atan2f(w1, w2) * INV2PI;
        }
    }
}

// ---- kernel 2: gather + stick-break + fp16 MFMA + folded-sin + reduce ----
__global__ __launch_bounds__(512, 4)
void nest2_mfma(const int* __restrict__ indices,
                const float* __restrict__ v0, const float* __restrict__ v1,
                const float* __restrict__ v2, const float* __restrict__ v3,
                const _Float16* __restrict__ Bh,
                const float* __restrict__ wa, const float* __restrict__ bb2,
                float* __restrict__ out)
{
    __shared__ alignas(16) _Float16 Ah[ROWS * ASTR];
    __shared__ float red[8][ROWS];

    const int tid = threadIdx.x;
    const int rowBase = blockIdx.x * ROWS;
    const int wid  = __builtin_amdgcn_readfirstlane(tid >> 6);   // 0..7
    const int lane = tid & 63;
    const int l15  = lane & 15;
    const int lg   = lane >> 4;
    const int wcol0 = wid * 64;    // this wave's 64-col slice

    #define BOFF(ch, ni) ((((ch) * 4 + lg) * 512 + wcol0 + (ni) * 16 + l15) * 8)

    // ---- folded epilogue constants first (in flight with everything) ----
    float bbv[NNI], wav[NNI];
    #pragma unroll
    for (int ni = 0; ni < NNI; ++ni) {
        const int c = wcol0 + ni * 16 + l15;
        wav[ni] = wa[c];
        bbv[ni] = bb2[c];
    }

    // ---- gather loads (wave-uniform row addresses -> coalesced) ----
    const int* ip = indices + rowBase * 4 + wid * 16;
    const float* vts[4] = {v0, v1, v2, v3};
    float vh[16];
    #pragma unroll
    for (int it = 0; it < 16; ++it) {
        const int mod = it & 3;            // wid*16 ≡ 0 (mod 4)
        vh[it] = vts[mod][ip[it] * RR + lane];
    }

    // ---- prefetch ch-0 AND ch-1 B fragments (2-deep pipeline) ----
    half8 b[NNI], bn[NNI];
    #pragma unroll
    for (int ni = 0; ni < NNI; ++ni) {
        b[ni]  = *reinterpret_cast<const half8*>(&Bh[BOFF(0, ni)]);
        bn[ni] = *reinterpret_cast<const half8*>(&Bh[BOFF(1, ni)]);
    }

    // ---- stick-breaking via DPP product-scan -> Ah (fp16) ----
    #pragma unroll
    for (int it = 0; it < 16; ++it) {
        const int p   = wid * 16 + it;     // 128 (row,mod) pairs per block
        const int row = p >> 2;
        const int mod = p & 3;
        const float t  = __expf(vh[it]);                    // e^{vh}
        const float um = __builtin_amdgcn_rcpf(1.f + t);    // sigmoid(-vh)
        float pr = um;                                      // inclusive scan
        pr *= dpp_mov1<0x111, 0xF>(pr);   // row_shr:1
        pr *= dpp_mov1<0x112, 0xF>(pr);   // row_shr:2
        pr *= dpp_mov1<0x114, 0xF>(pr);   // row_shr:4
        pr *= dpp_mov1<0x118, 0xF>(pr);   // row_shr:8
        pr *= dpp_mov1<0x142, 0xA>(pr);   // row_bcast:15
        pr *= dpp_mov1<0x143, 0xC>(pr);   // row_bcast:31
        const float x = t * pr;           // sigmoid(vh) * exclusive-prod
        Ah[row * ASTR + mod * RR + lane] = (_Float16)x;
    }
    __syncthreads();

    // ---- fp16 MFMA K-loop, 2-deep register pipeline on B ----
    floatx4 acc[MI][NNI];
    #pragma unroll
    for (int mi = 0; mi < MI; ++mi)
        #pragma unroll
        for (int ni = 0; ni < NNI; ++ni)
            acc[mi][ni] = (floatx4){0.f, 0.f, 0.f, 0.f};

    #pragma unroll
    for (int ch = 0; ch < NCH; ++ch) {
        half8 ah[MI];
        #pragma unroll
        for (int mi = 0; mi < MI; ++mi)
            ah[mi] = *reinterpret_cast<const half8*>(
                &Ah[(mi * 16 + l15) * ASTR + ch * 32 + lg * 8]);
        half8 b2[NNI];
        if (ch + 2 < NCH) {
            #pragma unroll
            for (int ni = 0; ni < NNI; ++ni)
                b2[ni] = *reinterpret_cast<const half8*>(&Bh[BOFF(ch + 2, ni)]);
        }
        __builtin_amdgcn_s_setprio(1);
        #pragma unroll
        for (int ni = 0; ni < NNI; ++ni)
            #pragma unroll
            for (int mi = 0; mi < MI; ++mi)
                acc[mi][ni] = __builtin_amdgcn_mfma_f32_16x16x32_f16(ah[mi], b[ni], acc[mi][ni], 0, 0, 0);
        __builtin_amdgcn_s_setprio(0);
        #pragma unroll
        for (int ni = 0; ni < NNI; ++ni) {
            b[ni] = bn[ni];
            if (ch + 2 < NCH) bn[ni] = b2[ni];
        }
    }

    // ---- epilogue: A*sin(2pi(x+phi')), reduce ----
    float rp[MI][4];
    #pragma unroll
    for (int mi = 0; mi < MI; ++mi)
        #pragma unroll
        for (int r = 0; r < 4; ++r) rp[mi][r] = 0.f;

    #pragma unroll
    for (int ni = 0; ni < NNI; ++ni) {
        #pragma unroll
        for (int mi = 0; mi < MI; ++mi)
            #pragma unroll
            for (int r = 0; r < 4; ++r) {
                const float psi = acc[mi][ni][r] + bbv[ni];   // revolutions
                rp[mi][r] = fmaf(wav[ni], __builtin_amdgcn_sinf(psi), rp[mi][r]);
            }
    }

    #pragma unroll
    for (int mi = 0; mi < MI; ++mi)
        #pragma unroll
        for (int r = 0; r < 4; ++r) {
            const float v = red16(rp[mi][r]);                 // sum over 16 cols
            if (l15 == 0) red[wid][mi * 16 + lg * 4 + r] = v;
        }
    __syncthreads();

    if (tid < ROWS) {
        float s = 0.f;
        #pragma unroll
        for (int w = 0; w < 8; ++w) s += red[w][tid];
        out[rowBase + tid] = 1.f / (1.f + __expf(-s));
    }
    #undef BOFF
}

extern "C" void kernel_launch(void* const* d_in, const int* in_sizes, int n_in,
                              void* d_out, int out_size, void* d_ws, size_t ws_size,
                              hipStream_t stream) {
    const int*   indices = (const int*)d_in[0];
    const float* v0 = (const float*)d_in[1];
    const float* v1 = (const float*)d_in[2];
    const float* v2 = (const float*)d_in[3];
    const float* v3 = (const float*)d_in[4];
    const float* S  = (const float*)d_in[5];
    const float* bb = (const float*)d_in[6];
    const float* w  = (const float*)d_in[7];
    float* out = (float*)d_out;

    char* wsb = (char*)d_ws;
    _Float16* Bh  = (_Float16*)wsb;                  // 256 KB
    float*    wa  = (float*)(wsb + 262144);          // 2 KB
    float*    bb2 = (float*)(wsb + 264192);          // 2 KB

    hipLaunchKernelGGL(prep, dim3(65), dim3(256), 0, stream,
                       S, bb, w, Bh, wa, bb2);
    hipLaunchKernelGGL(nest2_mfma, dim3(B_TOTAL / ROWS), dim3(512), 0, stream,
                       indices, v0, v1, v2, v3, Bh, wa, bb2, out);
}